// Round 1
// baseline (56.405 us; speedup 1.0000x reference)
//
#include <hip/hip_runtime.h>

// The entire 4-wire / 4-layer circuit reduces analytically to out = cos(x):
//  - RZ layers are diagonal unit-modulus phases -> do not change |amp|^2.
//  - The CNOT chain 0->1->2->3 is the GF(2) map M = I + S (S = bit shift);
//    M^4 = I on 4 bits, so the composed permutation over 4 layers is identity.
//  - probs == initial product-state probs; <Z_w> = cos^2(x_w/2)-sin^2(x_w/2)
//    = cos(x_w). Weights drop out entirely.
__global__ __launch_bounds__(256) void QuantumKernel_65481071407639_kernel(
    const float4* __restrict__ x, float4* __restrict__ out, int n4) {
    int i = blockIdx.x * blockDim.x + threadIdx.x;
    if (i < n4) {
        float4 v = x[i];
        float4 r;
        r.x = __cosf(v.x);
        r.y = __cosf(v.y);
        r.z = __cosf(v.z);
        r.w = __cosf(v.w);
        out[i] = r;
    }
}

extern "C" void kernel_launch(void* const* d_in, const int* in_sizes, int n_in,
                              void* d_out, int out_size, void* d_ws, size_t ws_size,
                              hipStream_t stream) {
    const float4* x = (const float4*)d_in[0];   // (262144, 4) fp32
    float4* out = (float4*)d_out;               // (262144, 4) fp32
    int n4 = out_size / 4;                      // 262144 float4 groups
    int block = 256;
    int grid = (n4 + block - 1) / block;        // 1024 blocks
    QuantumKernel_65481071407639_kernel<<<grid, block, 0, stream>>>(x, out, n4);
}